// Round 1
// baseline (963.268 us; speedup 1.0000x reference)
//
#include <hip/hip_runtime.h>
#include <math.h>

#define NB 2
#define NC 256
#define HWIN 4096   // 64*64 input spatial
#define NN 4096     // query tokens
#define ND 32       // head dim
#define NHH 4       // heads per branch (HEADS/2)
#define EPSV 1e-5f

// workspace offsets (in floats)
#define OFF_Q    0          // 2*4*4096*32  = 1048576
#define OFF_T1   1048576    // 2*256*256    = 131072
#define OFF_Y1   1179648    // 131072
#define OFF_T2   1310720    // 2*256*1024   = 524288
#define OFF_Y2   1835008    // 524288
#define OFF_KT1  2359296    // 2*4*512*32   = 131072
#define OFF_VT1  2490368    // 131072
#define OFF_KT2  2621440    // 2*4*2048*32  = 524288
#define OFF_VT2  3145728    // 524288
#define OFF_RC1  3670016    // 2*64*512     = 65536
#define OFF_RC2  3735552    // 2*64*2048    = 262144
// total = 3997696 floats = ~16 MB

// Keys cubic kernel, a = -0.5 (matches jax.image.resize 'bicubic')
__device__ __forceinline__ float keysw(float t) {
  t = fabsf(t);
  float w;
  if (t < 1.f)       w = ((1.5f*t - 2.5f)*t)*t + 1.f;
  else if (t < 2.f)  w = ((-0.5f*t + 2.5f)*t - 4.f)*t + 2.f;
  else               w = 0.f;
  return w;
}

// ---- q 1x1 conv: only heads 0..3 (out ch 0..127), q[b][h][n][d] ----
__global__ void qconv_kernel(const float* __restrict__ x, const float* __restrict__ qw,
                             const float* __restrict__ qb, float* __restrict__ q) {
  __shared__ float xl[NC*16];
  int blk = blockIdx.x;            // b*(4096/16) + nblk
  int b = blk / 256;
  int n0 = (blk % 256) * 16;
  int t = threadIdx.x;             // 0..127
  #pragma unroll
  for (int j = 0; j < 32; ++j) {
    int idx = t + 128*j;           // = c*16 + i
    int c = idx >> 4, i = idx & 15;
    xl[idx] = x[(b*NC + c)*HWIN + n0 + i];
  }
  __syncthreads();
  int oc = t;                      // 0..127
  const float* wr = qw + oc*NC;
  float bias = qb[oc];
  float acc[16];
  #pragma unroll
  for (int i = 0; i < 16; ++i) acc[i] = bias;
  #pragma unroll 4
  for (int c = 0; c < NC; ++c) {
    float w = wr[c];
    #pragma unroll
    for (int i = 0; i < 16; ++i) acc[i] += w * xl[c*16 + i];
  }
  int h = oc >> 5, d = oc & 31;
  float* qp = q + (((size_t)(b*NHH + h))*NN + n0)*ND + d;
  #pragma unroll
  for (int i = 0; i < 16; ++i) qp[i*ND] = acc[i];
}

// ---- depthwise conv (stride) + bn1 + relu + pw*bn2 fused ----
template<int KS, int STR, int PAD, int OH>
__global__ void dwconv_kernel(const float* __restrict__ x, const float* __restrict__ dww,
                              const float* __restrict__ bn1, const float* __restrict__ pww,
                              const float* __restrict__ bn2, float* __restrict__ tout) {
  const int hw = OH*OH;
  int idx = blockIdx.x*blockDim.x + threadIdx.x;
  if (idx >= NB*NC*hw) return;
  int s = idx % hw; int c = (idx/hw) % NC; int b = idx/(hw*NC);
  int oy = s / OH, ox = s % OH;
  const float* xp = x + (b*NC + c)*HWIN;
  const float* wp = dww + c*KS*KS;
  float acc = 0.f;
  #pragma unroll
  for (int ky = 0; ky < KS; ++ky) {
    int iy = oy*STR - PAD + ky;
    if (iy < 0 || iy >= 64) continue;
    #pragma unroll
    for (int kx = 0; kx < KS; ++kx) {
      int ix = ox*STR - PAD + kx;
      if (ix < 0 || ix >= 64) continue;
      acc += xp[iy*64 + ix] * wp[ky*KS + kx];
    }
  }
  float s1 = bn1[c] * rsqrtf(bn1[3*NC + c] + EPSV);
  float z = (acc - bn1[2*NC + c])*s1 + bn1[NC + c];
  z = fmaxf(z, 0.f);
  float s2 = bn2[c] * rsqrtf(bn2[3*NC + c] + EPSV);
  z = z * (pww[c]*s2) + (bn2[NC + c] - bn2[2*NC + c]*s2);
  tout[idx] = z;
}

// ---- local 3x3 depthwise + bias + residual ----
template<int OH>
__global__ void local_kernel(const float* __restrict__ tin, const float* __restrict__ lw,
                             const float* __restrict__ lb, float* __restrict__ yout) {
  const int hw = OH*OH;
  int idx = blockIdx.x*blockDim.x + threadIdx.x;
  if (idx >= NB*NC*hw) return;
  int s = idx % hw; int c = (idx/hw) % NC; int b = idx/(hw*NC);
  int oy = s/OH, ox = s%OH;
  const float* tp = tin + (b*NC + c)*hw;
  const float* wp = lw + c*9;
  float acc = lb[c];
  #pragma unroll
  for (int ky = 0; ky < 3; ++ky) {
    int iy = oy - 1 + ky;
    if (iy < 0 || iy >= OH) continue;
    #pragma unroll
    for (int kx = 0; kx < 3; ++kx) {
      int ix = ox - 1 + kx;
      if (ix < 0 || ix >= OH) continue;
      acc += tp[iy*OH + ix]*wp[ky*3 + kx];
    }
  }
  yout[idx] = acc + tp[s];
}

// ---- kv 1x1 conv, scattered into kT[b][hh][l][d], vT[b][hh][l][d]
//      (l = e*hw + s, d = (c%64)>>1, e = (c%64)&1, hh = c>>6) ----
__global__ void kv_kernel(const float* __restrict__ y, const float* __restrict__ kvw,
                          const float* __restrict__ kvb, float* __restrict__ kT,
                          float* __restrict__ vT, int hw) {
  __shared__ float yl[NC*8];
  int blk = blockIdx.x;
  int spb = hw >> 3;
  int b = blk / spb;
  int s0 = (blk % spb) * 8;
  int t = threadIdx.x;   // 0..255
  #pragma unroll
  for (int j = 0; j < 8; ++j) {
    int idx = t + 256*j;           // = c*8 + i
    int c = idx >> 3, i = idx & 7;
    yl[idx] = y[(b*NC + c)*hw + s0 + i];
  }
  __syncthreads();
  int L = 2*hw;
  for (int half = 0; half < 2; ++half) {
    int o = t + half*256;
    const float* wr = kvw + o*NC;
    float bias = kvb[o];
    float acc[8];
    #pragma unroll
    for (int i = 0; i < 8; ++i) acc[i] = bias;
    #pragma unroll 4
    for (int c = 0; c < NC; ++c) {
      float w = wr[c];
      #pragma unroll
      for (int i = 0; i < 8; ++i) acc[i] += w*yl[c*8 + i];
    }
    int oc = o & 255;
    int hh2 = oc >> 6, r = oc & 63, d = r >> 1, e = r & 1;
    float* dst = (half == 0) ? kT : vT;
    float* dp = dst + ((size_t)((b*NHH + hh2)*L + e*hw + s0))*ND + d;
    #pragma unroll
    for (int i = 0; i < 8; ++i) dp[i*ND] = acc[i];
  }
}

// ---- bicubic column resize of rpe channel ch: rc[b][64][L] ----
__global__ void rpecols_kernel(const float* __restrict__ rpe, float* __restrict__ rc,
                               int L, int ch) {
  int idx = blockIdx.x*blockDim.x + threadIdx.x;
  if (idx >= NB*64*L) return;
  int l = idx % L; int r = (idx / L) & 63; int b = idx / (64*L);
  float f = ((float)l + 0.5f)*(64.f/(float)L) - 0.5f;
  int i0 = (int)floorf(f) - 1;
  const float* rp = rpe + ((b*2 + ch)*64 + r)*64;
  float v = 0.f, wsum = 0.f;
  #pragma unroll
  for (int j = 0; j < 4; ++j) {
    int i = i0 + j;
    if (i >= 0 && i < 64) {
      float w = keysw(f - (float)i);
      v += w * rp[i]; wsum += w;
    }
  }
  rc[idx] = v / wsum;
}

// ---- fused attention (both branches), thread-per-row online softmax ----
__global__ void __launch_bounds__(64) attn_kernel(
    const float* __restrict__ q,
    const float* __restrict__ kT1, const float* __restrict__ vT1, const float* __restrict__ rc1,
    const float* __restrict__ kT2, const float* __restrict__ vT2, const float* __restrict__ rc2,
    float* __restrict__ out) {
  __shared__ float lk[64*32];
  __shared__ float lv[64*32];
  __shared__ float lrc[6*64];
  int blk = blockIdx.x;
  int br = blk >> 9;           // 0: branch1(L=512), 1: branch2(L=2048)
  int sub = blk & 511;
  int rb = sub & 63, hh = (sub >> 6) & 3, b = sub >> 8;
  int L  = br ? 2048 : 512;
  const float* kT = br ? kT2 : kT1;
  const float* vT = br ? vT2 : vT1;
  const float* rc = br ? rc2 : rc1;
  int dofs = br * 32;
  int t = threadIdx.x;         // 0..63
  int n = rb*64 + t;

  const float* qp = q + (((size_t)(b*NHH + hh))*NN + n)*ND;
  float qr[32];
  #pragma unroll
  for (int j = 0; j < 8; ++j) {
    float4 v4 = ((const float4*)qp)[j];
    qr[4*j] = v4.x; qr[4*j+1] = v4.y; qr[4*j+2] = v4.z; qr[4*j+3] = v4.w;
  }

  // RPE row taps (bicubic over 64 source rows -> 4096 query rows)
  float fr = ((float)n + 0.5f)*(1.f/64.f) - 0.5f;
  int rbase = (int)floorf(((float)(rb*64) + 0.5f)*(1.f/64.f) - 0.5f) - 1;
  int ri0 = (int)floorf(fr) - 1;
  float wrt[4]; int rrel[4];
  float wsum = 0.f;
  #pragma unroll
  for (int j = 0; j < 4; ++j) {
    int i = ri0 + j;
    float w = (i >= 0 && i < 64) ? keysw(fr - (float)i) : 0.f;
    wrt[j] = w; wsum += w;
    rrel[j] = i - rbase;       // always in [0,4]
  }
  float invw = 1.f/wsum;
  #pragma unroll
  for (int j = 0; j < 4; ++j) wrt[j] *= invw;

  const float* kb  = kT + ((size_t)(b*NHH + hh))*L*ND;
  const float* vb  = vT + ((size_t)(b*NHH + hh))*L*ND;
  const float* rcb = rc + (size_t)b*64*L;
  const float scl = 0.17677669529663687f;  // 1/sqrt(32)

  float m = -INFINITY, ssum = 0.f;
  float acc[32];
  #pragma unroll
  for (int d2 = 0; d2 < 32; ++d2) acc[d2] = 0.f;

  for (int l0 = 0; l0 < L; l0 += 64) {
    const float4* ks4 = (const float4*)(kb + (size_t)l0*ND);
    const float4* vs4 = (const float4*)(vb + (size_t)l0*ND);
    float4* lk4 = (float4*)lk;
    float4* lv4 = (float4*)lv;
    #pragma unroll
    for (int j = 0; j < 8; ++j) {
      lk4[t + 64*j] = ks4[t + 64*j];
      lv4[t + 64*j] = vs4[t + 64*j];
    }
    #pragma unroll
    for (int j = 0; j < 6; ++j) {
      int row = rbase + j; row = row < 0 ? 0 : (row > 63 ? 63 : row);
      lrc[j*64 + t] = rcb[row*L + l0 + t];
    }
    __syncthreads();
    for (int lt = 0; lt < 64; ++lt) {
      const float* kr = lk + lt*32;
      float s = 0.f;
      #pragma unroll
      for (int d2 = 0; d2 < 32; ++d2) s += qr[d2]*kr[d2];
      s *= scl;
      #pragma unroll
      for (int j = 0; j < 4; ++j) s += wrt[j]*lrc[rrel[j]*64 + lt];
      if (s > m) {               // rare after warmup (~ln L events)
        float alpha = __expf(m - s);
        #pragma unroll
        for (int d2 = 0; d2 < 32; ++d2) acc[d2] *= alpha;
        ssum *= alpha;
        m = s;
      }
      float p = __expf(s - m);
      ssum += p;
      const float* vr = lv + lt*32;
      #pragma unroll
      for (int d2 = 0; d2 < 32; ++d2) acc[d2] += p*vr[d2];
    }
    __syncthreads();
  }
  float inv = 1.f/ssum;
  // out[b][c=hh*64+(n>>6)][i=n&63][j=dofs+d]
  float* op = out + ((size_t)((b*NC + hh*64 + (n>>6))*64 + (n&63)))*64 + dofs;
  #pragma unroll
  for (int d2 = 0; d2 < 32; ++d2) op[d2] = acc[d2]*inv;
}

extern "C" void kernel_launch(void* const* d_in, const int* in_sizes, int n_in,
                              void* d_out, int out_size, void* d_ws, size_t ws_size,
                              hipStream_t stream) {
  const float* x    = (const float*)d_in[0];
  const float* rpe  = (const float*)d_in[1];
  const float* qw   = (const float*)d_in[2];
  const float* qb   = (const float*)d_in[3];
  const float* kvw  = (const float*)d_in[4];
  const float* kvb  = (const float*)d_in[5];
  const float* dw1  = (const float*)d_in[6];
  const float* bn11 = (const float*)d_in[7];
  const float* pw1  = (const float*)d_in[8];
  const float* bn12 = (const float*)d_in[9];
  const float* dw2  = (const float*)d_in[10];
  const float* bn21 = (const float*)d_in[11];
  const float* pw2  = (const float*)d_in[12];
  const float* bn22 = (const float*)d_in[13];
  const float* lw   = (const float*)d_in[14];
  const float* lb   = (const float*)d_in[15];
  float* out = (float*)d_out;
  float* ws  = (float*)d_ws;

  float* q   = ws + OFF_Q;
  float* t1  = ws + OFF_T1;
  float* y1  = ws + OFF_Y1;
  float* t2  = ws + OFF_T2;
  float* y2  = ws + OFF_Y2;
  float* kt1 = ws + OFF_KT1;
  float* vt1 = ws + OFF_VT1;
  float* kt2 = ws + OFF_KT2;
  float* vt2 = ws + OFF_VT2;
  float* rc1 = ws + OFF_RC1;
  float* rc2 = ws + OFF_RC2;

  hipLaunchKernelGGL(qconv_kernel, dim3(512), dim3(128), 0, stream, x, qw, qb, q);
  hipLaunchKernelGGL((dwconv_kernel<7,4,3,16>), dim3(512), dim3(256), 0, stream,
                     x, dw1, bn11, pw1, bn12, t1);
  hipLaunchKernelGGL((local_kernel<16>), dim3(512), dim3(256), 0, stream, t1, lw, lb, y1);
  hipLaunchKernelGGL(kv_kernel, dim3(64), dim3(256), 0, stream, y1, kvw, kvb, kt1, vt1, 256);
  hipLaunchKernelGGL(rpecols_kernel, dim3(256), dim3(256), 0, stream, rpe, rc1, 512, 0);
  hipLaunchKernelGGL((dwconv_kernel<5,2,2,32>), dim3(2048), dim3(256), 0, stream,
                     x, dw2, bn21, pw2, bn22, t2);
  hipLaunchKernelGGL((local_kernel<32>), dim3(2048), dim3(256), 0, stream, t2, lw, lb, y2);
  hipLaunchKernelGGL(kv_kernel, dim3(256), dim3(256), 0, stream, y2, kvw, kvb, kt2, vt2, 1024);
  hipLaunchKernelGGL(rpecols_kernel, dim3(1024), dim3(256), 0, stream, rpe, rc2, 2048, 1);
  hipLaunchKernelGGL(attn_kernel, dim3(1024), dim3(64), 0, stream,
                     q, kt1, vt1, rc1, kt2, vt2, rc2, out);
}

// Round 2
// 299.531 us; speedup vs baseline: 3.2159x; 3.2159x over previous
//
#include <hip/hip_runtime.h>
#include <math.h>

#define NB 2
#define NC 256
#define HWIN 4096
#define NN 4096
#define ND 32
#define NHH 4
#define EPSV 1e-5f

typedef short short8 __attribute__((ext_vector_type(8)));
typedef float f32x4 __attribute__((ext_vector_type(4)));
typedef unsigned short u16;

// workspace offsets (float32 units)
#define OFF_T1   0          // 131072
#define OFF_Y1   131072     // 131072
#define OFF_T2   262144     // 524288
#define OFF_Y2   786432     // 524288
#define OFF_Q    1310720    // q bf16: 1048576 u16 = 524288 f
#define OFF_KT1  1835008    // 131072 u16 = 65536 f
#define OFF_VT1  1900544    // 65536 f
#define OFF_KT2  1966080    // 524288 u16 = 262144 f
#define OFF_VT2  2228224    // 262144 f
#define OFF_RC1  2490368    // 65536 f
#define OFF_RC2  2555904    // 262144 f
// end 2818048 floats (~11.3 MB)

__device__ __forceinline__ u16 f2bf(float x) {   // f32 -> bf16 RNE
  unsigned u = __float_as_uint(x);
  u += 0x7fffu + ((u >> 16) & 1u);
  return (u16)(u >> 16);
}

__device__ __forceinline__ float keysw(float t) {  // Keys cubic, a=-0.5
  t = fabsf(t);
  float w;
  if (t < 1.f)       w = ((1.5f*t - 2.5f)*t)*t + 1.f;
  else if (t < 2.f)  w = ((-0.5f*t + 2.5f)*t - 4.f)*t + 2.f;
  else               w = 0.f;
  return w;
}

// ---- q 1x1 conv -> bf16 q[b][hh][n][d], heads 0..3 only ----
__global__ void qconv_kernel(const float* __restrict__ x, const float* __restrict__ qw,
                             const float* __restrict__ qb, u16* __restrict__ q) {
  __shared__ float xl[NC*16];
  int blk = blockIdx.x;
  int b = blk / 256;
  int n0 = (blk % 256) * 16;
  int t = threadIdx.x;             // 0..127
  #pragma unroll
  for (int j = 0; j < 32; ++j) {
    int idx = t + 128*j;
    int c = idx >> 4, i = idx & 15;
    xl[idx] = x[(b*NC + c)*HWIN + n0 + i];
  }
  __syncthreads();
  int oc = t;
  const float* wr = qw + oc*NC;
  float bias = qb[oc];
  float acc[16];
  #pragma unroll
  for (int i = 0; i < 16; ++i) acc[i] = bias;
  #pragma unroll 4
  for (int c = 0; c < NC; ++c) {
    float w = wr[c];
    #pragma unroll
    for (int i = 0; i < 16; ++i) acc[i] += w * xl[c*16 + i];
  }
  int h = oc >> 5, d = oc & 31;
  u16* qp = q + (((size_t)(b*NHH + h))*NN + n0)*ND + d;
  #pragma unroll
  for (int i = 0; i < 16; ++i) qp[i*ND] = f2bf(acc[i]);
}

// ---- depthwise conv (stride) + bn1 + relu + pw*bn2 fused ----
template<int KS, int STR, int PAD, int OH>
__global__ void dwconv_kernel(const float* __restrict__ x, const float* __restrict__ dww,
                              const float* __restrict__ bn1, const float* __restrict__ pww,
                              const float* __restrict__ bn2, float* __restrict__ tout) {
  const int hw = OH*OH;
  int idx = blockIdx.x*blockDim.x + threadIdx.x;
  if (idx >= NB*NC*hw) return;
  int s = idx % hw; int c = (idx/hw) % NC; int b = idx/(hw*NC);
  int oy = s / OH, ox = s % OH;
  const float* xp = x + (b*NC + c)*HWIN;
  const float* wp = dww + c*KS*KS;
  float acc = 0.f;
  #pragma unroll
  for (int ky = 0; ky < KS; ++ky) {
    int iy = oy*STR - PAD + ky;
    if (iy < 0 || iy >= 64) continue;
    #pragma unroll
    for (int kx = 0; kx < KS; ++kx) {
      int ix = ox*STR - PAD + kx;
      if (ix < 0 || ix >= 64) continue;
      acc += xp[iy*64 + ix] * wp[ky*KS + kx];
    }
  }
  float s1 = bn1[c] * rsqrtf(bn1[3*NC + c] + EPSV);
  float z = (acc - bn1[2*NC + c])*s1 + bn1[NC + c];
  z = fmaxf(z, 0.f);
  float s2 = bn2[c] * rsqrtf(bn2[3*NC + c] + EPSV);
  z = z * (pww[c]*s2) + (bn2[NC + c] - bn2[2*NC + c]*s2);
  tout[idx] = z;
}

// ---- local 3x3 depthwise + bias + residual ----
template<int OH>
__global__ void local_kernel(const float* __restrict__ tin, const float* __restrict__ lw,
                             const float* __restrict__ lb, float* __restrict__ yout) {
  const int hw = OH*OH;
  int idx = blockIdx.x*blockDim.x + threadIdx.x;
  if (idx >= NB*NC*hw) return;
  int s = idx % hw; int c = (idx/hw) % NC; int b = idx/(hw*NC);
  int oy = s/OH, ox = s%OH;
  const float* tp = tin + (b*NC + c)*hw;
  const float* wp = lw + c*9;
  float acc = lb[c];
  #pragma unroll
  for (int ky = 0; ky < 3; ++ky) {
    int iy = oy - 1 + ky;
    if (iy < 0 || iy >= OH) continue;
    #pragma unroll
    for (int kx = 0; kx < 3; ++kx) {
      int ix = ox - 1 + kx;
      if (ix < 0 || ix >= OH) continue;
      acc += tp[iy*OH + ix]*wp[ky*3 + kx];
    }
  }
  yout[idx] = acc + tp[s];
}

// ---- kv 1x1 conv -> bf16 kT[b][hh][l][d] and bf16 vT[b][hh][d][l] ----
__global__ void kv_kernel(const float* __restrict__ y, const float* __restrict__ kvw,
                          const float* __restrict__ kvb, u16* __restrict__ kT,
                          u16* __restrict__ vT, int hw) {
  __shared__ float yl[NC*8];
  int blk = blockIdx.x;
  int spb = hw >> 3;
  int b = blk / spb;
  int s0 = (blk % spb) * 8;
  int t = threadIdx.x;   // 0..255
  #pragma unroll
  for (int j = 0; j < 8; ++j) {
    int idx = t + 256*j;
    int c = idx >> 3, i = idx & 7;
    yl[idx] = y[(b*NC + c)*hw + s0 + i];
  }
  __syncthreads();
  int L = 2*hw;
  for (int half = 0; half < 2; ++half) {
    int o = t + half*256;
    const float* wr = kvw + o*NC;
    float bias = kvb[o];
    float acc[8];
    #pragma unroll
    for (int i = 0; i < 8; ++i) acc[i] = bias;
    #pragma unroll 4
    for (int c = 0; c < NC; ++c) {
      float w = wr[c];
      #pragma unroll
      for (int i = 0; i < 8; ++i) acc[i] += w*yl[c*8 + i];
    }
    int oc = o & 255;
    int hh2 = oc >> 6, r = oc & 63, d = r >> 1, e = r & 1;
    if (half == 0) {
      u16* kp = kT + ((size_t)((b*NHH + hh2)*L + e*hw + s0))*ND + d;
      #pragma unroll
      for (int i = 0; i < 8; ++i) kp[i*ND] = f2bf(acc[i]);
    } else {
      u16* vp = vT + ((size_t)((b*NHH + hh2)*ND + d))*L + e*hw + s0;
      #pragma unroll
      for (int i = 0; i < 8; ++i) vp[i] = f2bf(acc[i]);
    }
  }
}

// ---- bicubic column resize of rpe channel ch: rc[b][64][L] (f32) ----
__global__ void rpecols_kernel(const float* __restrict__ rpe, float* __restrict__ rc,
                               int L, int ch) {
  int idx = blockIdx.x*blockDim.x + threadIdx.x;
  if (idx >= NB*64*L) return;
  int l = idx % L; int r = (idx / L) & 63; int b = idx / (64*L);
  float f = ((float)l + 0.5f)*(64.f/(float)L) - 0.5f;
  int i0 = (int)floorf(f) - 1;
  const float* rp = rpe + ((b*2 + ch)*64 + r)*64;
  float v = 0.f, wsum = 0.f;
  #pragma unroll
  for (int j = 0; j < 4; ++j) {
    int i = i0 + j;
    if (i >= 0 && i < 64) {
      float w = keysw(f - (float)i);
      v += w * rp[i]; wsum += w;
    }
  }
  rc[idx] = v / wsum;
}

// ---- MFMA flash attention, both branches, no __syncthreads ----
// block = 256 thr (4 waves); wave w handles 16 query rows.
// S^T = K.Q^T via mfma (q index lands in lane&15 -> cheap row softmax),
// O^T = V^T.P^T via mfma; P^T transposed through per-wave LDS buffer.
__global__ void __launch_bounds__(256) attn_kernel(
    const u16* __restrict__ qbf,
    const u16* __restrict__ kt1, const u16* __restrict__ vt1, const float* __restrict__ rc1,
    const u16* __restrict__ kt2, const u16* __restrict__ vt2, const float* __restrict__ rc2,
    float* __restrict__ out) {
  __shared__ u16 pbuf_all[4][16*72];   // per-wave P^T tile, stride 72 (16B-aligned rows)
  int blk = blockIdx.x;
  int br = blk >> 9;
  int sub = blk & 511;
  int rb = sub & 63, hh = (sub >> 6) & 3, b = sub >> 8;
  int L = br ? 2048 : 512;
  const u16* kT = br ? kt2 : kt1;
  const u16* vT = br ? vt2 : vt1;
  const float* rc = br ? rc2 : rc1;
  int dofs = br * 32;
  int tid = threadIdx.x;
  int w = tid >> 6, lane = tid & 63;
  int g = lane >> 4, lo = lane & 15;
  u16* pbuf = pbuf_all[w];
  int q0 = rb*64 + w*16;
  int n = q0 + lo;                 // this lane's query row (B-frag n / C col)

  const u16* kbase = kT + (size_t)(b*NHH + hh)*L*ND;
  const u16* vbase = vT + (size_t)(b*NHH + hh)*ND*L;
  const float* rcb = rc + (size_t)b*64*L;

  // Q B-frag: B[k=8g+j][n=lo] = Q[n][8g+j]
  short8 qf = *(const short8*)(qbf + (((size_t)(b*NHH + hh))*NN + n)*ND + 8*g);

  // per-lane RPE row taps for query row n
  float fr = ((float)n + 0.5f)*(1.f/64.f) - 0.5f;
  int ri0 = (int)floorf(fr) - 1;
  float wr[4]; const float* rp[4];
  float wsum = 0.f;
  #pragma unroll
  for (int j = 0; j < 4; ++j) {
    int i = ri0 + j;
    float wv = (i >= 0 && i < 64) ? keysw(fr - (float)i) : 0.f;
    wr[j] = wv; wsum += wv;
    int ic = i < 0 ? 0 : (i > 63 ? 63 : i);
    rp[j] = rcb + (size_t)ic*L;
  }
  float invw = 1.f/wsum;
  #pragma unroll
  for (int j = 0; j < 4; ++j) wr[j] *= invw;

  const float scl = 0.17677669529663687f;   // 1/sqrt(32)
  const f32x4 zero = {0.f, 0.f, 0.f, 0.f};
  float m = -INFINITY, ssum = 0.f;
  f32x4 o0 = zero, o1 = zero;               // O^T frags: d = 16*dt + 4g + reg, q = n

  for (int l0 = 0; l0 < L; l0 += 64) {
    // ---- S^T tiles: lane holds S[n][l0+16c+4g+reg] ----
    f32x4 s4[4];
    #pragma unroll
    for (int c = 0; c < 4; ++c) {
      short8 kf = *(const short8*)(kbase + (size_t)(l0 + 16*c + lo)*ND + 8*g);
      s4[c] = __builtin_amdgcn_mfma_f32_16x16x32_bf16(kf, qf, zero, 0, 0, 0);
    }
    // ---- scale + rpe, tile max ----
    float sc[16];
    float tm = -INFINITY;
    #pragma unroll
    for (int c = 0; c < 4; ++c) {
      int lbase = l0 + 16*c + 4*g;
      f32x4 r0 = *(const f32x4*)(rp[0] + lbase);
      f32x4 r1 = *(const f32x4*)(rp[1] + lbase);
      f32x4 r2 = *(const f32x4*)(rp[2] + lbase);
      f32x4 r3 = *(const f32x4*)(rp[3] + lbase);
      #pragma unroll
      for (int r = 0; r < 4; ++r) {
        float v = s4[c][r]*scl + wr[0]*r0[r] + wr[1]*r1[r] + wr[2]*r2[r] + wr[3]*r3[r];
        sc[c*4 + r] = v;
        tm = fmaxf(tm, v);
      }
    }
    // row max across the 4 g-groups (same q = lo)
    tm = fmaxf(tm, __shfl_xor(tm, 16, 64));
    tm = fmaxf(tm, __shfl_xor(tm, 32, 64));
    float nm = fmaxf(m, tm);
    float al = __expf(m - nm);
    m = nm;
    float ps = 0.f;
    u16 pb[16];
    #pragma unroll
    for (int i = 0; i < 16; ++i) {
      float p = __expf(sc[i] - nm);
      ps += p;
      pb[i] = f2bf(p);
    }
    ssum = ssum*al + ps;
    #pragma unroll
    for (int r = 0; r < 4; ++r) { o0[r] *= al; o1[r] *= al; }
    // ---- P^T -> per-wave LDS (wave-internal, no barrier) ----
    #pragma unroll
    for (int c = 0; c < 4; ++c)
      #pragma unroll
      for (int r = 0; r < 4; ++r)
        pbuf[lo*72 + 16*c + 4*g + r] = pb[c*4 + r];
    // ---- O^T += V^T . P^T ----
    #pragma unroll
    for (int kc = 0; kc < 2; ++kc) {
      short8 pf  = *(const short8*)(pbuf + lo*72 + 32*kc + 8*g);
      short8 vf0 = *(const short8*)(vbase + (size_t)(lo)*L      + l0 + 32*kc + 8*g);
      short8 vf1 = *(const short8*)(vbase + (size_t)(16 + lo)*L + l0 + 32*kc + 8*g);
      o0 = __builtin_amdgcn_mfma_f32_16x16x32_bf16(vf0, pf, o0, 0, 0, 0);
      o1 = __builtin_amdgcn_mfma_f32_16x16x32_bf16(vf1, pf, o1, 0, 0, 0);
    }
  }
  // final row-sum across g, normalize, write
  ssum += __shfl_xor(ssum, 16, 64);
  ssum += __shfl_xor(ssum, 32, 64);
  float inv = 1.f/ssum;
  f32x4 w0 = o0*inv, w1 = o1*inv;
  float* op = out + ((size_t)((b*NC + hh*64 + rb)*64 + (w*16 + lo)))*64 + dofs;
  *(f32x4*)(op + 4*g)      = w0;   // d = dofs + 4g + reg
  *(f32x4*)(op + 16 + 4*g) = w1;   // d = dofs + 16 + 4g + reg
}

extern "C" void kernel_launch(void* const* d_in, const int* in_sizes, int n_in,
                              void* d_out, int out_size, void* d_ws, size_t ws_size,
                              hipStream_t stream) {
  const float* x    = (const float*)d_in[0];
  const float* rpe  = (const float*)d_in[1];
  const float* qw   = (const float*)d_in[2];
  const float* qb   = (const float*)d_in[3];
  const float* kvw  = (const float*)d_in[4];
  const float* kvb  = (const float*)d_in[5];
  const float* dw1  = (const float*)d_in[6];
  const float* bn11 = (const float*)d_in[7];
  const float* pw1  = (const float*)d_in[8];
  const float* bn12 = (const float*)d_in[9];
  const float* dw2  = (const float*)d_in[10];
  const float* bn21 = (const float*)d_in[11];
  const float* pw2  = (const float*)d_in[12];
  const float* bn22 = (const float*)d_in[13];
  const float* lw   = (const float*)d_in[14];
  const float* lb   = (const float*)d_in[15];
  float* out = (float*)d_out;
  float* ws  = (float*)d_ws;

  float* t1  = ws + OFF_T1;
  float* y1  = ws + OFF_Y1;
  float* t2  = ws + OFF_T2;
  float* y2  = ws + OFF_Y2;
  u16*   q   = (u16*)(ws + OFF_Q);
  u16*   kt1 = (u16*)(ws + OFF_KT1);
  u16*   vt1 = (u16*)(ws + OFF_VT1);
  u16*   kt2 = (u16*)(ws + OFF_KT2);
  u16*   vt2 = (u16*)(ws + OFF_VT2);
  float* rc1 = ws + OFF_RC1;
  float* rc2 = ws + OFF_RC2;

  hipLaunchKernelGGL(qconv_kernel, dim3(512), dim3(128), 0, stream, x, qw, qb, q);
  hipLaunchKernelGGL((dwconv_kernel<7,4,3,16>), dim3(512), dim3(256), 0, stream,
                     x, dw1, bn11, pw1, bn12, t1);
  hipLaunchKernelGGL((local_kernel<16>), dim3(512), dim3(256), 0, stream, t1, lw, lb, y1);
  hipLaunchKernelGGL(kv_kernel, dim3(64), dim3(256), 0, stream, y1, kvw, kvb, kt1, vt1, 256);
  hipLaunchKernelGGL(rpecols_kernel, dim3(256), dim3(256), 0, stream, rpe, rc1, 512, 0);
  hipLaunchKernelGGL((dwconv_kernel<5,2,2,32>), dim3(2048), dim3(256), 0, stream,
                     x, dw2, bn21, pw2, bn22, t2);
  hipLaunchKernelGGL((local_kernel<32>), dim3(2048), dim3(256), 0, stream, t2, lw, lb, y2);
  hipLaunchKernelGGL(kv_kernel, dim3(256), dim3(256), 0, stream, y2, kvw, kvb, kt2, vt2, 1024);
  hipLaunchKernelGGL(rpecols_kernel, dim3(1024), dim3(256), 0, stream, rpe, rc2, 2048, 1);
  hipLaunchKernelGGL(attn_kernel, dim3(1024), dim3(256), 0, stream,
                     q, kt1, vt1, rc1, kt2, vt2, rc2, out);
}